// Round 7
// baseline (207.339 us; speedup 1.0000x reference)
//
#include <hip/hip_runtime.h>
#include <hip/hip_bf16.h>

// KascadeReuseAttention  B=1, S=2048, DM=1024, H=16, D=64, T=16, NA=3
// Round-7: (1) gemm_qkv retiled 64x128 -> 768 blocks = 3 perfect CU-waves
// (was 384 = 1.5 waves, 33% tail on the largest kernel); (2) conv_x+trans_w
// merged into one prep launch (each inter-dispatch gap ~8-10us); (3) attn
// phase-4 reads packed (tok<<16|bf16(w)) -> 16 broadcast DS reads vs 32.

#define S_LEN 2048
#define DM 1024
#define NH 16
#define HD 64
#define LDK 40  // LDS row stride (ushorts); 80 B: 16B-aligned, 0 conflicts (measured r4/r5)

typedef __bf16 bf16x8 __attribute__((ext_vector_type(8)));
typedef float f32x4 __attribute__((ext_vector_type(4)));

static __device__ __forceinline__ unsigned short f2bf(float f) {
    union { float f; unsigned int i; } un;
    un.f = f;
    unsigned int r = un.i + 0x7FFFu + ((un.i >> 16) & 1u);  // RNE
    return (unsigned short)(r >> 16);
}
static __device__ __forceinline__ float bfu2f(unsigned short u) {
    union { unsigned int i; float f; } un;
    un.i = ((unsigned int)u) << 16;
    return un.f;
}
static __device__ __forceinline__ float bflo(unsigned int u) {
    union { unsigned int i; float f; } un;
    un.i = u << 16;
    return un.f;
}
static __device__ __forceinline__ float bfhi(unsigned int u) {
    union { unsigned int i; float f; } un;
    un.i = u & 0xFFFF0000u;
    return un.f;
}

// ---------------------------------------------------------------------------
// prep: blocks [0,4096) transpose W* fp32->bf16 [n][k]; blocks [4096,5120)
// convert x fp32->bf16. One launch replaces conv_x + trans_w.
// ---------------------------------------------------------------------------
__global__ __launch_bounds__(256) void prep(
    const float* __restrict__ x, unsigned short* __restrict__ xb,
    const float* __restrict__ W0, const float* __restrict__ W1,
    const float* __restrict__ W2, const float* __restrict__ W3,
    unsigned short* __restrict__ T0, unsigned short* __restrict__ T1,
    unsigned short* __restrict__ T2, unsigned short* __restrict__ T3) {
    const int bx = blockIdx.x;
    if (bx < 4096) {
        const int z = bx >> 10, rem = bx & 1023;
        const float* W = (z == 0) ? W0 : (z == 1) ? W1 : (z == 2) ? W2 : W3;
        unsigned short* T = (z == 0) ? T0 : (z == 1) ? T1 : (z == 2) ? T2 : T3;
        __shared__ float t[32][33];
        const int bn = (rem & 31) * 32, bk = (rem >> 5) * 32;
        const int tx = threadIdx.x & 31, ty = threadIdx.x >> 5;
        #pragma unroll
        for (int m = 0; m < 4; ++m)
            t[ty + m * 8][tx] = W[(size_t)(bk + ty + m * 8) * 1024 + bn + tx];
        __syncthreads();
        #pragma unroll
        for (int m = 0; m < 4; ++m)
            T[(size_t)(bn + ty + m * 8) * 1024 + bk + tx] = f2bf(t[tx][ty + m * 8]);
    } else {
        const int i = (bx - 4096) * 2048 + threadIdx.x * 8;
        float4 f0 = *(const float4*)(x + i);
        float4 f1 = *(const float4*)(x + i + 4);
        ushort4 o0, o1;
        o0.x = f2bf(f0.x); o0.y = f2bf(f0.y); o0.z = f2bf(f0.z); o0.w = f2bf(f0.w);
        o1.x = f2bf(f1.x); o1.y = f2bf(f1.y); o1.z = f2bf(f1.z); o1.w = f2bf(f1.w);
        *(ushort4*)(xb + i) = o0;
        *(ushort4*)(xb + i + 4) = o1;
    }
}

// ---------------------------------------------------------------------------
// QKV GEMM: 64x128 tile, BK=32, 4 waves (2x2 of 32x64), bf16 MFMA 16x16x32.
// grid (24,32) = 768 blocks = 3 full CU-waves. Fused RoPE epilogue,
// head-major bf16 out [H][S][64].
// ---------------------------------------------------------------------------
__global__ __launch_bounds__(256) void gemm_qkv(
    const unsigned short* __restrict__ xb,
    const unsigned short* __restrict__ Wtq, const unsigned short* __restrict__ Wtk,
    const unsigned short* __restrict__ Wtv,
    unsigned short* __restrict__ qh, unsigned short* __restrict__ kh,
    unsigned short* __restrict__ vh,
    const float* __restrict__ cs, const float* __restrict__ sn) {
    __shared__ __align__(16) unsigned short Al[64 * LDK];
    __shared__ __align__(16) unsigned short Bl[128 * LDK];
    const int tid = threadIdx.x;
    const int nb = blockIdx.x >> 3;
    const unsigned short* __restrict__ Bt = (nb == 0) ? Wtq : (nb == 1) ? Wtk : Wtv;
    unsigned short* __restrict__ OUT = (nb == 0) ? qh : (nb == 1) ? kh : vh;
    const int col0 = (blockIdx.x & 7) * 128;
    const int row0 = blockIdx.y * 64;
    const int lane = tid & 63, wvi = tid >> 6;
    const int wr = (wvi >> 1) * 32, wc = (wvi & 1) * 64;
    const int l15 = lane & 15, quad = lane >> 4;
    const int rowA = tid >> 2, kqA = (tid & 3) << 3;   // 8 el/thread
    const int rowB = tid >> 1, kqB = (tid & 1) << 4;   // 16 el/thread

    f32x4 acc[2][4] = {};
    for (int k0 = 0; k0 < 1024; k0 += 32) {
        const uint4 a0 = *(const uint4*)(xb + (size_t)(row0 + rowA) * 1024 + k0 + kqA);
        const unsigned short* gb = Bt + (size_t)(col0 + rowB) * 1024 + k0 + kqB;
        const uint4 b0 = *(const uint4*)gb;
        const uint4 b1 = *(const uint4*)(gb + 8);
        __syncthreads();
        *(uint4*)&Al[rowA * LDK + kqA] = a0;
        unsigned short* bd = &Bl[rowB * LDK + kqB];
        *(uint4*)bd = b0; *(uint4*)(bd + 8) = b1;
        __syncthreads();
        bf16x8 af[2], bfr[4];
        #pragma unroll
        for (int i = 0; i < 2; ++i)
            af[i] = *(const bf16x8*)&Al[(wr + i * 16 + l15) * LDK + quad * 8];
        #pragma unroll
        for (int j = 0; j < 4; ++j)
            bfr[j] = *(const bf16x8*)&Bl[(wc + j * 16 + l15) * LDK + quad * 8];
        #pragma unroll
        for (int i = 0; i < 2; ++i)
            #pragma unroll
            for (int j = 0; j < 4; ++j)
                acc[i][j] = __builtin_amdgcn_mfma_f32_16x16x32_bf16(
                    af[i], bfr[j], acc[i][j], 0, 0, 0);
    }

    // epilogue: wave's 64 cols = one head; dims d=j*16+l15, RoPE pairs (j,j+2)
    const int hh = ((blockIdx.x & 7) << 1) + (wc >> 6);
    const bool dorope = (nb != 2);
    #pragma unroll
    for (int i = 0; i < 2; ++i) {
        const int rowb = row0 + wr + i * 16 + quad * 4;
        #pragma unroll
        for (int r = 0; r < 4; ++r) {
            const int s = rowb + r;
            float v0 = acc[i][0][r], v1 = acc[i][1][r];
            float v2 = acc[i][2][r], v3 = acc[i][3][r];
            if (dorope) {
                float c0 = cs[s * 32 + l15],      s0 = sn[s * 32 + l15];
                float c1 = cs[s * 32 + 16 + l15], s1 = sn[s * 32 + 16 + l15];
                float lo0 = v0 * c0 - v2 * s0;
                float hi0 = v2 * c0 + v0 * s0;
                float lo1 = v1 * c1 - v3 * s1;
                float hi1 = v3 * c1 + v1 * s1;
                v0 = lo0; v1 = lo1; v2 = hi0; v3 = hi1;
            }
            unsigned short* op = OUT + (size_t)hh * (S_LEN * 64) + (size_t)s * 64 + l15;
            op[0]  = f2bf(v0);
            op[16] = f2bf(v1);
            op[32] = f2bf(v2);
            op[48] = f2bf(v3);
        }
    }
}

// ---------------------------------------------------------------------------
// Attention: one wave per (h,q). Wave-private LDS slices, same-address
// broadcast ds_reads. Phase 4 reads packed (tok<<16 | bf16(w)): 16 DS reads.
// ---------------------------------------------------------------------------
__global__ __launch_bounds__(256) void attn_kernel(
    const unsigned short* __restrict__ qh, const unsigned short* __restrict__ kh,
    const unsigned short* __restrict__ vh, const int* __restrict__ anc,
    unsigned short* __restrict__ att) {
    __shared__ __align__(16) float qs[4][64];
    __shared__ __align__(16) int   ts[4][64];
    __shared__ __align__(16) float ws[4][64];
    __shared__ __align__(16) unsigned int ps[4][64];
    const int w4 = threadIdx.x >> 6;
    const int lane = threadIdx.x & 63;
    const int wid = (blockIdx.x << 2) + w4;
    const int h = wid >> 11;
    const int qi = wid & 2047;
    const size_t hb = (size_t)h * (S_LEN * 64);

    // stage q + token into this wave's LDS slice
    const float q_own = bfu2f(qh[hb + (size_t)qi * 64 + lane]);
    const int slot = lane >> 4;
    const int tile = (slot < 3) ? anc[((size_t)h * S_LEN + qi) * 3 + slot]
                                : (qi >> 4);
    const int tok_own = tile * 16 + (lane & 15);
    qs[w4][lane] = q_own;
    ts[w4][lane] = tok_own;

    // hoisted q chunk: lane covers dims c*16..c*16+15 (broadcast b128 reads)
    const int c = lane & 3;
    const int t = lane >> 2;
    float qv[16];
    #pragma unroll
    for (int r = 0; r < 4; ++r) {
        float4 f = *(const float4*)&qs[w4][c * 16 + r * 4];
        qv[r * 4 + 0] = f.x; qv[r * 4 + 1] = f.y;
        qv[r * 4 + 2] = f.z; qv[r * 4 + 3] = f.w;
    }

    // phase 2: pass p covers tile slot p's 16 tokens (2 KB contiguous);
    // 4 lanes per token, width-4 butterfly reduce.
    #pragma unroll
    for (int p = 0; p < 4; ++p) {
        const int tk = ts[w4][p * 16 + t];  // broadcast ds_read
        const unsigned short* kp = kh + hb + (size_t)tk * 64 + c * 16;
        const uint4 k0 = *(const uint4*)kp;
        const uint4 k1 = *(const uint4*)(kp + 8);
        float part;
        part = bflo(k0.x) * qv[0];
        part = fmaf(bfhi(k0.x), qv[1], part);
        part = fmaf(bflo(k0.y), qv[2], part);
        part = fmaf(bfhi(k0.y), qv[3], part);
        part = fmaf(bflo(k0.z), qv[4], part);
        part = fmaf(bfhi(k0.z), qv[5], part);
        part = fmaf(bflo(k0.w), qv[6], part);
        part = fmaf(bfhi(k0.w), qv[7], part);
        part = fmaf(bflo(k1.x), qv[8], part);
        part = fmaf(bfhi(k1.x), qv[9], part);
        part = fmaf(bflo(k1.y), qv[10], part);
        part = fmaf(bfhi(k1.y), qv[11], part);
        part = fmaf(bflo(k1.z), qv[12], part);
        part = fmaf(bfhi(k1.z), qv[13], part);
        part = fmaf(bflo(k1.w), qv[14], part);
        part = fmaf(bfhi(k1.w), qv[15], part);
        part += __shfl_xor(part, 1, 64);
        part += __shfl_xor(part, 2, 64);
        if (c == 0) ws[w4][p * 16 + t] = part;  // exec-masked ds_write
    }

    // own logit + causal mask
    float logit = ws[w4][lane];
    const bool fut = tok_own > qi;  // local tile keeps tok==qi unmasked
    logit = fut ? -1e30f : logit * 0.125f;

    // wave softmax (duplicate tiles double-counted, as reference)
    float m = logit;
    #pragma unroll
    for (int off = 32; off >= 1; off >>= 1)
        m = fmaxf(m, __shfl_xor(m, off, 64));
    const float e = fut ? 0.f : __expf(logit - m);
    float ssum = e;
    #pragma unroll
    for (int off = 32; off >= 1; off >>= 1)
        ssum += __shfl_xor(ssum, off, 64);
    ps[w4][lane] = ((unsigned int)tok_own << 16) | f2bf(e / ssum);

    // phase 4: lane = dim; packed (tok,w) via broadcast b128 reads
    float out = 0.f;
    #pragma unroll
    for (int kk = 0; kk < 64; kk += 8) {
        const uint4 pa = *(const uint4*)&ps[w4][kk];
        const uint4 pb = *(const uint4*)&ps[w4][kk + 4];
        const unsigned int p8[8] = {pa.x, pa.y, pa.z, pa.w,
                                    pb.x, pb.y, pb.z, pb.w};
        float vv[8];
        #pragma unroll
        for (int j = 0; j < 8; ++j)
            vv[j] = bfu2f(vh[hb + (size_t)(p8[j] >> 16) * 64 + lane]);
        #pragma unroll
        for (int j = 0; j < 8; ++j)
            out = fmaf(bflo(p8[j]), vv[j], out);
    }
    att[(size_t)qi * DM + h * HD + lane] = f2bf(out);
}

// ---------------------------------------------------------------------------
// Out GEMM: out fp32 = att(bf16) @ Wto^T. 64x128 tile, grid (8,32).
// ---------------------------------------------------------------------------
__global__ __launch_bounds__(256) void gemm_out(
    const unsigned short* __restrict__ A, const unsigned short* __restrict__ Bt,
    float* __restrict__ C) {
    __shared__ __align__(16) unsigned short Al[64 * LDK];
    __shared__ __align__(16) unsigned short Bl[128 * LDK];
    const int tid = threadIdx.x;
    const int col0 = blockIdx.x * 128;
    const int row0 = blockIdx.y * 64;
    const int lane = tid & 63, wvi = tid >> 6;
    const int wr = (wvi >> 1) * 32, wc = (wvi & 1) * 64;
    const int l15 = lane & 15, quad = lane >> 4;
    const int rowA = tid >> 2, kqA = (tid & 3) << 3;
    const int rowB = tid >> 1, kqB = (tid & 1) << 4;

    f32x4 acc[2][4] = {};
    for (int k0 = 0; k0 < 1024; k0 += 32) {
        const uint4 a0 = *(const uint4*)(A + (size_t)(row0 + rowA) * 1024 + k0 + kqA);
        const unsigned short* gb = Bt + (size_t)(col0 + rowB) * 1024 + k0 + kqB;
        const uint4 b0 = *(const uint4*)gb;
        const uint4 b1 = *(const uint4*)(gb + 8);
        __syncthreads();
        *(uint4*)&Al[rowA * LDK + kqA] = a0;
        unsigned short* bd = &Bl[rowB * LDK + kqB];
        *(uint4*)bd = b0; *(uint4*)(bd + 8) = b1;
        __syncthreads();
        bf16x8 af[2], bfr[4];
        #pragma unroll
        for (int i = 0; i < 2; ++i)
            af[i] = *(const bf16x8*)&Al[(wr + i * 16 + l15) * LDK + quad * 8];
        #pragma unroll
        for (int j = 0; j < 4; ++j)
            bfr[j] = *(const bf16x8*)&Bl[(wc + j * 16 + l15) * LDK + quad * 8];
        #pragma unroll
        for (int i = 0; i < 2; ++i)
            #pragma unroll
            for (int j = 0; j < 4; ++j)
                acc[i][j] = __builtin_amdgcn_mfma_f32_16x16x32_bf16(
                    af[i], bfr[j], acc[i][j], 0, 0, 0);
    }
    #pragma unroll
    for (int i = 0; i < 2; ++i) {
        const int rowb = row0 + wr + i * 16 + quad * 4;
        #pragma unroll
        for (int r = 0; r < 4; ++r) {
            float* crow = C + (size_t)(rowb + r) * 1024 + col0 + wc;
            #pragma unroll
            for (int j = 0; j < 4; ++j)
                crow[j * 16 + l15] = acc[i][j][r];
        }
    }
}

// ---------------------------------------------------------------------------
extern "C" void kernel_launch(void* const* d_in, const int* in_sizes, int n_in,
                              void* d_out, int out_size, void* d_ws, size_t ws_size,
                              hipStream_t stream) {
    const float* x   = (const float*)d_in[0];
    const float* Wq  = (const float*)d_in[1];
    const float* Wk  = (const float*)d_in[2];
    const float* Wv  = (const float*)d_in[3];
    const float* Wo  = (const float*)d_in[4];
    const float* cs  = (const float*)d_in[5];
    const float* sn  = (const float*)d_in[6];
    const int*   anc = (const int*)d_in[7];
    float* out = (float*)d_out;

    unsigned short* xb  = (unsigned short*)d_ws;
    unsigned short* Wtq = xb  + (size_t)2048 * 1024;
    unsigned short* Wtk = Wtq + (size_t)1024 * 1024;
    unsigned short* Wtv = Wtk + (size_t)1024 * 1024;
    unsigned short* Wto = Wtv + (size_t)1024 * 1024;
    unsigned short* qh  = Wto + (size_t)1024 * 1024;   // [H][S][64]
    unsigned short* kh  = qh  + (size_t)2048 * 1024;
    unsigned short* vh  = kh  + (size_t)2048 * 1024;
    unsigned short* att = vh  + (size_t)2048 * 1024;   // [S][H*D]

    prep<<<5120, 256, 0, stream>>>(x, xb, Wq, Wk, Wv, Wo, Wtq, Wtk, Wtv, Wto);
    gemm_qkv<<<dim3(24, 32), 256, 0, stream>>>(xb, Wtq, Wtk, Wtv,
                                               qh, kh, vh, cs, sn);
    attn_kernel<<<(S_LEN * NH) / 4, 256, 0, stream>>>(qh, kh, vh, anc, att);
    gemm_out<<<dim3(8, 32), 256, 0, stream>>>(att, Wto, out);
}

// Round 8
// 163.796 us; speedup vs baseline: 1.2658x; 1.2658x over previous
//
#include <hip/hip_runtime.h>
#include <hip/hip_bf16.h>

// KascadeReuseAttention  B=1, S=2048, DM=1024, H=16, D=64, T=16, NA=3
// Round-8: revert to r6-measured kernels (attn packed-ps change in r7 doubled
// attn 45->82us: v-load addresses became dependent on the softmax chain,
// killing load prefetch; possible scratch demotion too). Keep r7's merged
// prep (one launch gap saved). attn phase-4 uses named scalars, addresses
// from ts (available at phase 1) so loads can issue under the softmax.

#define S_LEN 2048
#define DM 1024
#define NH 16
#define HD 64
#define LDK 40  // LDS row stride (ushorts); 80 B: 16B-aligned, 0 conflicts (measured)

typedef __bf16 bf16x8 __attribute__((ext_vector_type(8)));
typedef float f32x4 __attribute__((ext_vector_type(4)));

static __device__ __forceinline__ unsigned short f2bf(float f) {
    union { float f; unsigned int i; } un;
    un.f = f;
    unsigned int r = un.i + 0x7FFFu + ((un.i >> 16) & 1u);  // RNE
    return (unsigned short)(r >> 16);
}
static __device__ __forceinline__ float bfu2f(unsigned short u) {
    union { unsigned int i; float f; } un;
    un.i = ((unsigned int)u) << 16;
    return un.f;
}
static __device__ __forceinline__ float bflo(unsigned int u) {
    union { unsigned int i; float f; } un;
    un.i = u << 16;
    return un.f;
}
static __device__ __forceinline__ float bfhi(unsigned int u) {
    union { unsigned int i; float f; } un;
    un.i = u & 0xFFFF0000u;
    return un.f;
}

// ---------------------------------------------------------------------------
// prep: blocks [0,4096) transpose W* fp32->bf16 [n][k]; blocks [4096,5120)
// convert x fp32->bf16.
// ---------------------------------------------------------------------------
__global__ __launch_bounds__(256) void prep(
    const float* __restrict__ x, unsigned short* __restrict__ xb,
    const float* __restrict__ W0, const float* __restrict__ W1,
    const float* __restrict__ W2, const float* __restrict__ W3,
    unsigned short* __restrict__ T0, unsigned short* __restrict__ T1,
    unsigned short* __restrict__ T2, unsigned short* __restrict__ T3) {
    const int bx = blockIdx.x;
    if (bx < 4096) {
        const int z = bx >> 10, rem = bx & 1023;
        const float* W = (z == 0) ? W0 : (z == 1) ? W1 : (z == 2) ? W2 : W3;
        unsigned short* T = (z == 0) ? T0 : (z == 1) ? T1 : (z == 2) ? T2 : T3;
        __shared__ float t[32][33];
        const int bn = (rem & 31) * 32, bk = (rem >> 5) * 32;
        const int tx = threadIdx.x & 31, ty = threadIdx.x >> 5;
        #pragma unroll
        for (int m = 0; m < 4; ++m)
            t[ty + m * 8][tx] = W[(size_t)(bk + ty + m * 8) * 1024 + bn + tx];
        __syncthreads();
        #pragma unroll
        for (int m = 0; m < 4; ++m)
            T[(size_t)(bn + ty + m * 8) * 1024 + bk + tx] = f2bf(t[tx][ty + m * 8]);
    } else {
        const int i = (bx - 4096) * 2048 + threadIdx.x * 8;
        float4 f0 = *(const float4*)(x + i);
        float4 f1 = *(const float4*)(x + i + 4);
        ushort4 o0, o1;
        o0.x = f2bf(f0.x); o0.y = f2bf(f0.y); o0.z = f2bf(f0.z); o0.w = f2bf(f0.w);
        o1.x = f2bf(f1.x); o1.y = f2bf(f1.y); o1.z = f2bf(f1.z); o1.w = f2bf(f1.w);
        *(ushort4*)(xb + i) = o0;
        *(ushort4*)(xb + i + 4) = o1;
    }
}

// ---------------------------------------------------------------------------
// QKV GEMM (r6 config): 128x128 tile, BK=32, 4 waves (2x2 of 64x64), bf16
// MFMA 16x16x32. grid (24,16). Fused RoPE epilogue, head-major out [H][S][64].
// ---------------------------------------------------------------------------
__global__ __launch_bounds__(256) void gemm_qkv(
    const unsigned short* __restrict__ xb,
    const unsigned short* __restrict__ Wtq, const unsigned short* __restrict__ Wtk,
    const unsigned short* __restrict__ Wtv,
    unsigned short* __restrict__ qh, unsigned short* __restrict__ kh,
    unsigned short* __restrict__ vh,
    const float* __restrict__ cs, const float* __restrict__ sn) {
    __shared__ __align__(16) unsigned short Al[128 * LDK];
    __shared__ __align__(16) unsigned short Bl[128 * LDK];
    const int tid = threadIdx.x;
    const int nb = blockIdx.x >> 3;
    const unsigned short* __restrict__ Bt = (nb == 0) ? Wtq : (nb == 1) ? Wtk : Wtv;
    unsigned short* __restrict__ OUT = (nb == 0) ? qh : (nb == 1) ? kh : vh;
    const int col0 = (blockIdx.x & 7) * 128;
    const int row0 = blockIdx.y * 128;
    const int lane = tid & 63, wvi = tid >> 6;
    const int wr = (wvi >> 1) * 64, wc = (wvi & 1) * 64;
    const int l15 = lane & 15, quad = lane >> 4;
    const int srow = tid >> 1, skq = (tid & 1) << 4;

    f32x4 acc[4][4] = {};
    for (int k0 = 0; k0 < 1024; k0 += 32) {
        const unsigned short* ga = xb + (size_t)(row0 + srow) * 1024 + k0 + skq;
        uint4 a0 = *(const uint4*)ga;
        uint4 a1 = *(const uint4*)(ga + 8);
        const unsigned short* gb = Bt + (size_t)(col0 + srow) * 1024 + k0 + skq;
        uint4 b0 = *(const uint4*)gb;
        uint4 b1 = *(const uint4*)(gb + 8);
        __syncthreads();
        unsigned short* ad = &Al[srow * LDK + skq];
        *(uint4*)ad = a0; *(uint4*)(ad + 8) = a1;
        unsigned short* bd = &Bl[srow * LDK + skq];
        *(uint4*)bd = b0; *(uint4*)(bd + 8) = b1;
        __syncthreads();
        bf16x8 af[4], bfr[4];
        #pragma unroll
        for (int i = 0; i < 4; ++i)
            af[i] = *(const bf16x8*)&Al[(wr + i * 16 + l15) * LDK + quad * 8];
        #pragma unroll
        for (int j = 0; j < 4; ++j)
            bfr[j] = *(const bf16x8*)&Bl[(wc + j * 16 + l15) * LDK + quad * 8];
        #pragma unroll
        for (int i = 0; i < 4; ++i)
            #pragma unroll
            for (int j = 0; j < 4; ++j)
                acc[i][j] = __builtin_amdgcn_mfma_f32_16x16x32_bf16(
                    af[i], bfr[j], acc[i][j], 0, 0, 0);
    }

    const int hh = ((blockIdx.x & 7) << 1) + (wc >> 6);
    const bool dorope = (nb != 2);
    #pragma unroll
    for (int i = 0; i < 4; ++i) {
        const int rowb = row0 + wr + i * 16 + quad * 4;
        #pragma unroll
        for (int r = 0; r < 4; ++r) {
            const int s = rowb + r;
            float v0 = acc[i][0][r], v1 = acc[i][1][r];
            float v2 = acc[i][2][r], v3 = acc[i][3][r];
            if (dorope) {
                float c0 = cs[s * 32 + l15],      s0 = sn[s * 32 + l15];
                float c1 = cs[s * 32 + 16 + l15], s1 = sn[s * 32 + 16 + l15];
                float lo0 = v0 * c0 - v2 * s0;
                float hi0 = v2 * c0 + v0 * s0;
                float lo1 = v1 * c1 - v3 * s1;
                float hi1 = v3 * c1 + v1 * s1;
                v0 = lo0; v1 = lo1; v2 = hi0; v3 = hi1;
            }
            unsigned short* op = OUT + (size_t)hh * (S_LEN * 64) + (size_t)s * 64 + l15;
            op[0]  = f2bf(v0);
            op[16] = f2bf(v1);
            op[32] = f2bf(v2);
            op[48] = f2bf(v3);
        }
    }
}

// ---------------------------------------------------------------------------
// Attention (r6 dataflow): one wave per (h,q). Wave-private LDS slices;
// same-address broadcast ds_reads. Phase-4 addresses come from ts (written
// in phase 1) so v-loads can issue under the softmax chain. Named scalars
// only (no local arrays -> no scratch risk).
// ---------------------------------------------------------------------------
__global__ __launch_bounds__(256) void attn_kernel(
    const unsigned short* __restrict__ qh, const unsigned short* __restrict__ kh,
    const unsigned short* __restrict__ vh, const int* __restrict__ anc,
    unsigned short* __restrict__ att) {
    __shared__ __align__(16) float qs[4][64];
    __shared__ __align__(16) int   ts[4][64];
    __shared__ __align__(16) float ws[4][64];
    const int w4 = threadIdx.x >> 6;
    const int lane = threadIdx.x & 63;
    const int wid = (blockIdx.x << 2) + w4;
    const int h = wid >> 11;
    const int qi = wid & 2047;
    const size_t hb = (size_t)h * (S_LEN * 64);

    // phase 1: stage q + token into this wave's LDS slice
    const float q_own = bfu2f(qh[hb + (size_t)qi * 64 + lane]);
    const int slot = lane >> 4;
    const int tile = (slot < 3) ? anc[((size_t)h * S_LEN + qi) * 3 + slot]
                                : (qi >> 4);
    const int tok_own = tile * 16 + (lane & 15);
    qs[w4][lane] = q_own;
    ts[w4][lane] = tok_own;

    // hoisted q chunk: lane covers dims c*16..c*16+15 (broadcast b128 reads)
    const int c = lane & 3;
    const int t = lane >> 2;
    float qv[16];
    #pragma unroll
    for (int r = 0; r < 4; ++r) {
        float4 f = *(const float4*)&qs[w4][c * 16 + r * 4];
        qv[r * 4 + 0] = f.x; qv[r * 4 + 1] = f.y;
        qv[r * 4 + 2] = f.z; qv[r * 4 + 3] = f.w;
    }

    // phase 2: pass p covers tile slot p's 16 tokens (2 KB contiguous);
    // 4 lanes per token, width-4 butterfly reduce.
    #pragma unroll
    for (int p = 0; p < 4; ++p) {
        const int tk = ts[w4][p * 16 + t];  // broadcast ds_read
        const unsigned short* kp = kh + hb + (size_t)tk * 64 + c * 16;
        const uint4 k0 = *(const uint4*)kp;
        const uint4 k1 = *(const uint4*)(kp + 8);
        float part;
        part = bflo(k0.x) * qv[0];
        part = fmaf(bfhi(k0.x), qv[1], part);
        part = fmaf(bflo(k0.y), qv[2], part);
        part = fmaf(bfhi(k0.y), qv[3], part);
        part = fmaf(bflo(k0.z), qv[4], part);
        part = fmaf(bfhi(k0.z), qv[5], part);
        part = fmaf(bflo(k0.w), qv[6], part);
        part = fmaf(bfhi(k0.w), qv[7], part);
        part = fmaf(bflo(k1.x), qv[8], part);
        part = fmaf(bfhi(k1.x), qv[9], part);
        part = fmaf(bflo(k1.y), qv[10], part);
        part = fmaf(bfhi(k1.y), qv[11], part);
        part = fmaf(bflo(k1.z), qv[12], part);
        part = fmaf(bfhi(k1.z), qv[13], part);
        part = fmaf(bflo(k1.w), qv[14], part);
        part = fmaf(bfhi(k1.w), qv[15], part);
        part += __shfl_xor(part, 1, 64);
        part += __shfl_xor(part, 2, 64);
        if (c == 0) ws[w4][p * 16 + t] = part;  // exec-masked ds_write
    }

    // own logit + causal mask
    float logit = ws[w4][lane];
    const bool fut = tok_own > qi;  // local tile keeps tok==qi unmasked
    logit = fut ? -1e30f : logit * 0.125f;

    // wave softmax (duplicate tiles double-counted, as reference)
    float m = logit;
    #pragma unroll
    for (int off = 32; off >= 1; off >>= 1)
        m = fmaxf(m, __shfl_xor(m, off, 64));
    const float e = fut ? 0.f : __expf(logit - m);
    float ssum = e;
    #pragma unroll
    for (int off = 32; off >= 1; off >>= 1)
        ssum += __shfl_xor(ssum, off, 64);
    ws[w4][lane] = e / ssum;

    // phase 4: lane = dim; tokens via broadcast b128 reads of ts (early
    // addresses), weights via broadcast b128 reads of ws. Named scalars.
    const unsigned short* vb = vh + hb + lane;
    float out = 0.f;
    #pragma unroll
    for (int kk = 0; kk < 64; kk += 8) {
        const int4 ta = *(const int4*)&ts[w4][kk];
        const int4 tb = *(const int4*)&ts[w4][kk + 4];
        const float v0 = bfu2f(vb[(size_t)ta.x * 64]);
        const float v1 = bfu2f(vb[(size_t)ta.y * 64]);
        const float v2 = bfu2f(vb[(size_t)ta.z * 64]);
        const float v3 = bfu2f(vb[(size_t)ta.w * 64]);
        const float v4 = bfu2f(vb[(size_t)tb.x * 64]);
        const float v5 = bfu2f(vb[(size_t)tb.y * 64]);
        const float v6 = bfu2f(vb[(size_t)tb.z * 64]);
        const float v7 = bfu2f(vb[(size_t)tb.w * 64]);
        const float4 wa = *(const float4*)&ws[w4][kk];
        const float4 wb = *(const float4*)&ws[w4][kk + 4];
        out = fmaf(wa.x, v0, out);
        out = fmaf(wa.y, v1, out);
        out = fmaf(wa.z, v2, out);
        out = fmaf(wa.w, v3, out);
        out = fmaf(wb.x, v4, out);
        out = fmaf(wb.y, v5, out);
        out = fmaf(wb.z, v6, out);
        out = fmaf(wb.w, v7, out);
    }
    att[(size_t)qi * DM + h * HD + lane] = f2bf(out);
}

// ---------------------------------------------------------------------------
// Out GEMM: out fp32 = att(bf16) @ Wto^T. 64x128 tile, grid (8,32).
// ---------------------------------------------------------------------------
__global__ __launch_bounds__(256) void gemm_out(
    const unsigned short* __restrict__ A, const unsigned short* __restrict__ Bt,
    float* __restrict__ C) {
    __shared__ __align__(16) unsigned short Al[64 * LDK];
    __shared__ __align__(16) unsigned short Bl[128 * LDK];
    const int tid = threadIdx.x;
    const int col0 = blockIdx.x * 128;
    const int row0 = blockIdx.y * 64;
    const int lane = tid & 63, wvi = tid >> 6;
    const int wr = (wvi >> 1) * 32, wc = (wvi & 1) * 64;
    const int l15 = lane & 15, quad = lane >> 4;
    const int rowA = tid >> 2, kqA = (tid & 3) << 3;
    const int rowB = tid >> 1, kqB = (tid & 1) << 4;

    f32x4 acc[2][4] = {};
    for (int k0 = 0; k0 < 1024; k0 += 32) {
        const uint4 a0 = *(const uint4*)(A + (size_t)(row0 + rowA) * 1024 + k0 + kqA);
        const unsigned short* gb = Bt + (size_t)(col0 + rowB) * 1024 + k0 + kqB;
        const uint4 b0 = *(const uint4*)gb;
        const uint4 b1 = *(const uint4*)(gb + 8);
        __syncthreads();
        *(uint4*)&Al[rowA * LDK + kqA] = a0;
        unsigned short* bd = &Bl[rowB * LDK + kqB];
        *(uint4*)bd = b0; *(uint4*)(bd + 8) = b1;
        __syncthreads();
        bf16x8 af[2], bfr[4];
        #pragma unroll
        for (int i = 0; i < 2; ++i)
            af[i] = *(const bf16x8*)&Al[(wr + i * 16 + l15) * LDK + quad * 8];
        #pragma unroll
        for (int j = 0; j < 4; ++j)
            bfr[j] = *(const bf16x8*)&Bl[(wc + j * 16 + l15) * LDK + quad * 8];
        #pragma unroll
        for (int i = 0; i < 2; ++i)
            #pragma unroll
            for (int j = 0; j < 4; ++j)
                acc[i][j] = __builtin_amdgcn_mfma_f32_16x16x32_bf16(
                    af[i], bfr[j], acc[i][j], 0, 0, 0);
    }
    #pragma unroll
    for (int i = 0; i < 2; ++i) {
        const int rowb = row0 + wr + i * 16 + quad * 4;
        #pragma unroll
        for (int r = 0; r < 4; ++r) {
            float* crow = C + (size_t)(rowb + r) * 1024 + col0 + wc;
            #pragma unroll
            for (int j = 0; j < 4; ++j)
                crow[j * 16 + l15] = acc[i][j][r];
        }
    }
}

// ---------------------------------------------------------------------------
extern "C" void kernel_launch(void* const* d_in, const int* in_sizes, int n_in,
                              void* d_out, int out_size, void* d_ws, size_t ws_size,
                              hipStream_t stream) {
    const float* x   = (const float*)d_in[0];
    const float* Wq  = (const float*)d_in[1];
    const float* Wk  = (const float*)d_in[2];
    const float* Wv  = (const float*)d_in[3];
    const float* Wo  = (const float*)d_in[4];
    const float* cs  = (const float*)d_in[5];
    const float* sn  = (const float*)d_in[6];
    const int*   anc = (const int*)d_in[7];
    float* out = (float*)d_out;

    unsigned short* xb  = (unsigned short*)d_ws;
    unsigned short* Wtq = xb  + (size_t)2048 * 1024;
    unsigned short* Wtk = Wtq + (size_t)1024 * 1024;
    unsigned short* Wtv = Wtk + (size_t)1024 * 1024;
    unsigned short* Wto = Wtv + (size_t)1024 * 1024;
    unsigned short* qh  = Wto + (size_t)1024 * 1024;   // [H][S][64]
    unsigned short* kh  = qh  + (size_t)2048 * 1024;
    unsigned short* vh  = kh  + (size_t)2048 * 1024;
    unsigned short* att = vh  + (size_t)2048 * 1024;   // [S][H*D]

    prep<<<5120, 256, 0, stream>>>(x, xb, Wq, Wk, Wv, Wo, Wtq, Wtk, Wtv, Wto);
    gemm_qkv<<<dim3(24, 16), 256, 0, stream>>>(xb, Wtq, Wtk, Wtv,
                                               qh, kh, vh, cs, sn);
    attn_kernel<<<(S_LEN * NH) / 4, 256, 0, stream>>>(qh, kh, vh, anc, att);
    gemm_out<<<dim3(8, 32), 256, 0, stream>>>(att, Wto, out);
}